// Round 1
// 97.023 us; speedup vs baseline: 1.0918x; 1.0918x over previous
//
#include <hip/hip_runtime.h>

#define MARGIN 0.3f
#define EPS 1e-6f

constexpr int B = 64, N = 512, D = 512;
constexpr int NIDS = 32;          // track ids in [-1, 32)

constexpr int MB_THREADS = 256;
constexpr int MB_WAVES = MB_THREADS / 64;            // 4
constexpr int ANCH_PER_WAVE = 8;                     // 2 chunks of 4, prefetched
constexpr int A_BLOCK = MB_WAVES * ANCH_PER_WAVE;    // 32 anchors per block
constexpr int MB_BLOCKS = (B * N) / A_BLOCK;         // 1024 (16 blocks per batch)

// ws layout: float psum[1024]; float pcnt[1024]

__global__ __launch_bounds__(MB_THREADS) void tl_fused(const float* __restrict__ feats,
                                                       const int* __restrict__ ids,
                                                       float* __restrict__ psum,
                                                       float* __restrict__ pcnt) {
    __shared__ int s_ids[N];                  // 2 KB
    __shared__ int s_first[NIDS], s_second[NIDS];
    __shared__ int s_j0, s_jdiff, s_vcnt;
    __shared__ float s_wsum[MB_WAVES];
    __shared__ int s_wcnt[MB_WAVES];

    const int t = threadIdx.x;
    const int lane = t & 63;
    const int wave = t >> 6;

    // XCD swizzle: XCD x (= blockIdx%8) owns logical blocks x*128..x*128+127,
    // i.e. 8 whole batches -> gathers stay in the local L2.
    const int logical = ((blockIdx.x & 7) << 7) | (blockIdx.x >> 3);
    const int b = logical >> 4;                  // 16 blocks per batch
    const int seg = (logical & 15) * A_BLOCK;    // first anchor of this block
    const float* __restrict__ bf = feats + (size_t)b * N * D;
    const int* __restrict__ bi = ids + b * N;

    // ---- inline per-batch table build (replaces the tl_tables kernel) ----
    // 256 threads cover 512 positions: thread t owns positions t and t+256.
    const int v0 = bi[t];
    const int v1 = bi[t + 256];
    s_ids[t] = v0;
    s_ids[t + 256] = v1;
    if (t < NIDS) { s_first[t] = N; s_second[t] = N; }
    if (t == 0) { s_j0 = N; s_jdiff = N; s_vcnt = 0; }
    __syncthreads();

    // pass 1: first occurrence per id, first valid position, valid count.
    {
        const unsigned long long m0 = __ballot(v0 >= 0);
        const unsigned long long m1 = __ballot(v1 >= 0);
        if (lane == 0) {
            const int add = __popcll(m0) + __popcll(m1);
            if (add) atomicAdd(&s_vcnt, add);
            if (m0) atomicMin(&s_j0, (wave << 6) + __builtin_ctzll(m0));
            if (m1) atomicMin(&s_j0, 256 + (wave << 6) + __builtin_ctzll(m1));
        }
        if (v0 >= 0) atomicMin(&s_first[v0], t);
        if (v1 >= 0) atomicMin(&s_first[v1], t + 256);
    }
    __syncthreads();

    const int j0 = s_j0;
    const int id0 = (j0 < N) ? s_ids[j0] : -2;

    // pass 2: second occurrence per id, first valid position with id != id0.
    {
        if (v0 >= 0 && s_first[v0] != t) atomicMin(&s_second[v0], t);
        if (v1 >= 0 && s_first[v1] != t + 256) atomicMin(&s_second[v1], t + 256);
        const unsigned long long d0 = __ballot(v0 >= 0 && v0 != id0);
        const unsigned long long d1 = __ballot(v1 >= 0 && v1 != id0);
        if (lane == 0) {
            if (d0) atomicMin(&s_jdiff, (wave << 6) + __builtin_ctzll(d0));
            if (d1) atomicMin(&s_jdiff, 256 + (wave << 6) + __builtin_ctzll(d1));
        }
    }
    __syncthreads();

    const int jdiff = s_jdiff;
    const int vcnt = s_vcnt;
    const int j0c = min(j0, N - 1), jdc = min(jdiff, N - 1);

    // Register-cache the two negative-candidate rows of this batch.
    const float4* n0p = (const float4*)(bf + (size_t)j0c * D) + lane * 2;
    const float4* n1p = (const float4*)(bf + (size_t)jdc * D) + lane * 2;
    const float4 n0a = n0p[0], n0b = n0p[1];
    const float4 n1a = n1p[0], n1b = n1p[1];

    float wsum = 0.0f;
    int wcnt = 0;

    #pragma unroll
    for (int c = 0; c < ANCH_PER_WAVE / 4; ++c) {
        const int lbase = wave * ANCH_PER_WAVE + c * 4;   // local anchor index

        int pj[4]; bool okk[4]; bool useN0[4];
        #pragma unroll
        for (int k = 0; k < 4; ++k) {
            const int li = lbase + k;
            const int i = seg + li;
            const int vi = s_ids[seg + li];
            bool ok = (vi >= 0) && (vcnt >= 2);
            int posj = 0, negj = 0;
            if (ok) {
                // argmax of bool mask = first True
                const int f = s_first[vi];
                posj = (f != i) ? f : s_second[vi];
                negj = (vi != id0) ? j0 : jdiff;
                ok = (posj < N) && (negj < N);
            }
            okk[k] = ok;
            pj[k] = ok ? posj : 0;
            useN0[k] = (negj == j0);
        }

        // Issue all 16 independent 16B loads before any compute.
        float4 A0[4], A1[4], P0[4], P1[4];
        #pragma unroll
        for (int k = 0; k < 4; ++k) {
            const int i = seg + lbase + k;
            const float4* fa = (const float4*)(bf + (size_t)i * D) + lane * 2;
            const float4* fp = (const float4*)(bf + (size_t)pj[k] * D) + lane * 2;
            A0[k] = fa[0]; A1[k] = fa[1];
            P0[k] = fp[0]; P1[k] = fp[1];
        }

        #pragma unroll
        for (int k = 0; k < 4; ++k) {
            const float4 m0 = useN0[k] ? n0a : n1a;
            const float4 m1 = useN0[k] ? n0b : n1b;
            float sap = 0.0f, san = 0.0f, dd;
            dd = A0[k].x - P0[k].x + EPS; sap += dd * dd;
            dd = A0[k].y - P0[k].y + EPS; sap += dd * dd;
            dd = A0[k].z - P0[k].z + EPS; sap += dd * dd;
            dd = A0[k].w - P0[k].w + EPS; sap += dd * dd;
            dd = A1[k].x - P1[k].x + EPS; sap += dd * dd;
            dd = A1[k].y - P1[k].y + EPS; sap += dd * dd;
            dd = A1[k].z - P1[k].z + EPS; sap += dd * dd;
            dd = A1[k].w - P1[k].w + EPS; sap += dd * dd;
            dd = A0[k].x - m0.x + EPS; san += dd * dd;
            dd = A0[k].y - m0.y + EPS; san += dd * dd;
            dd = A0[k].z - m0.z + EPS; san += dd * dd;
            dd = A0[k].w - m0.w + EPS; san += dd * dd;
            dd = A1[k].x - m1.x + EPS; san += dd * dd;
            dd = A1[k].y - m1.y + EPS; san += dd * dd;
            dd = A1[k].z - m1.z + EPS; san += dd * dd;
            dd = A1[k].w - m1.w + EPS; san += dd * dd;

            #pragma unroll
            for (int off = 32; off >= 1; off >>= 1) {
                sap += __shfl_xor(sap, off);
                san += __shfl_xor(san, off);
            }
            const float per = fmaxf(sqrtf(sap) - sqrtf(san) + MARGIN, 0.0f);
            wsum += okk[k] ? per : 0.0f;
            wcnt += okk[k] ? 1 : 0;
        }
    }

    if (lane == 0) { s_wsum[wave] = wsum; s_wcnt[wave] = wcnt; }
    __syncthreads();
    if (t == 0) {
        float s = 0.0f; int c = 0;
        #pragma unroll
        for (int w = 0; w < MB_WAVES; ++w) { s += s_wsum[w]; c += s_wcnt[w]; }
        psum[blockIdx.x] = s;
        pcnt[blockIdx.x] = (float)c;
    }
}

__global__ __launch_bounds__(256) void tl_finalize(const float* __restrict__ psum,
                                                   const float* __restrict__ pcnt,
                                                   float* __restrict__ out) {
    __shared__ float s_s[4], s_c[4];
    const int t = threadIdx.x;
    float s = 0.0f, c = 0.0f;
    for (int k = t; k < MB_BLOCKS; k += 256) { s += psum[k]; c += pcnt[k]; }
    #pragma unroll
    for (int off = 32; off >= 1; off >>= 1) {
        s += __shfl_xor(s, off);
        c += __shfl_xor(c, off);
    }
    if ((t & 63) == 0) { s_s[t >> 6] = s; s_c[t >> 6] = c; }
    __syncthreads();
    if (t == 0) {
        const float S = s_s[0] + s_s[1] + s_s[2] + s_s[3];
        const float C = s_c[0] + s_c[1] + s_c[2] + s_c[3];
        const float loss = (C > 0.0f) ? (S / C) : 0.0f;
        out[0] = loss;   // tracking_loss = triplet + id(=0)
        out[1] = loss;   // loss_triplet
        out[2] = 0.0f;   // loss_id
    }
}

extern "C" void kernel_launch(void* const* d_in, const int* in_sizes, int n_in,
                              void* d_out, int out_size, void* d_ws, size_t ws_size,
                              hipStream_t stream) {
    const float* feats = (const float*)d_in[0];  // (B,N,D) fp32
    const int* ids = (const int*)d_in[1];        // (B,N) int32
    float* out = (float*)d_out;                  // 3 fp32 scalars

    char* ws = (char*)d_ws;
    float* psum = (float*)ws;                    // 1024 floats
    float* pcnt = psum + MB_BLOCKS;              // 1024 floats

    tl_fused<<<MB_BLOCKS, MB_THREADS, 0, stream>>>(feats, ids, psum, pcnt);
    tl_finalize<<<1, 256, 0, stream>>>(psum, pcnt, out);
}